// Round 4
// baseline (244.843 us; speedup 1.0000x reference)
//
#include <hip/hip_runtime.h>

typedef unsigned short u16;
typedef __attribute__((ext_vector_type(8))) short bf16x8;
typedef __attribute__((ext_vector_type(8))) unsigned short u16x8;
typedef __attribute__((ext_vector_type(4))) unsigned u32x4;
typedef __attribute__((ext_vector_type(4))) float f32x4;

#define DEVI static __device__ __forceinline__

DEVI u16 f2b(float f) {
  unsigned u = __builtin_bit_cast(unsigned, f);
  return (u16)((u + 0x7FFFu + ((u >> 16) & 1u)) >> 16);
}

DEVI unsigned cvtpk(float a, float b) {  // lo16 = bf16(a), hi16 = bf16(b)
  unsigned r;
  asm("v_cvt_pk_bf16_f32 %0, %1, %2" : "=v"(r) : "v"(a), "v"(b));
  return r;
}

DEVI void gload_lds16(const void* g, void* l) {
  __builtin_amdgcn_global_load_lds(
      (const __attribute__((address_space(1))) unsigned int*)g,
      (__attribute__((address_space(3))) unsigned int*)l, 16, 0, 0);
}

// ---------------- prep kernels ----------------

__global__ __launch_bounds__(256) void prep_x(const float* __restrict__ x, u16* __restrict__ xb) {
  const int n8 = 65536 * 256 / 8;
  int i = blockIdx.x * blockDim.x + threadIdx.x;
  for (; i < n8; i += gridDim.x * blockDim.x) {
    const float4* p = (const float4*)x + (size_t)i * 2;
    float4 a = p[0], b = p[1];
    u16x8 r;
    r[0] = f2b(a.x); r[1] = f2b(a.y); r[2] = f2b(a.z); r[3] = f2b(a.w);
    r[4] = f2b(b.x); r[5] = f2b(b.y); r[6] = f2b(b.z); r[7] = f2b(b.w);
    *(u16x8*)(xb + (size_t)i * 8) = r;
  }
}

// wqkvT[1536][256]: row n<512 -> Wq[:,n]*0.125 ; 512..1023 -> Wk ; 1024.. -> Wv
// woT[256][512]: row n -> Wo[:,n] ;  bqkv[1536] = concat(bq*0.125, bk, bv)
__global__ __launch_bounds__(256) void prep_w(
    const float* __restrict__ Wq, const float* __restrict__ Wk,
    const float* __restrict__ Wv, const float* __restrict__ Wo,
    const float* __restrict__ bq, const float* __restrict__ bk, const float* __restrict__ bv,
    u16* __restrict__ wqkvT, u16* __restrict__ woT, float* __restrict__ bqkv) {
  const int NW1 = 1536 * 256, NW2 = 256 * 512;
  const int total = NW1 + NW2 + 1536;
  int i = blockIdx.x * blockDim.x + threadIdx.x;
  for (; i < total; i += gridDim.x * blockDim.x) {
    if (i < NW1) {
      int nn = i >> 8, kk = i & 255;
      float v;
      if (nn < 512)       v = Wq[kk * 512 + nn] * 0.125f;
      else if (nn < 1024) v = Wk[kk * 512 + (nn - 512)];
      else                v = Wv[kk * 512 + (nn - 1024)];
      wqkvT[i] = f2b(v);
    } else if (i < NW1 + NW2) {
      int j = i - NW1;
      int nn = j >> 9, kk = j & 511;
      woT[j] = f2b(Wo[kk * 256 + nn]);
    } else {
      int j = i - NW1 - NW2;
      bqkv[j] = (j < 512) ? bq[j] * 0.125f : (j < 1024 ? bk[j - 512] : bv[j - 1024]);
    }
  }
}

// ---------------- GEMM: C[M,N] = A[M,K](bf16) * Bt[N,K]^T(bf16) + bias ----------------
// (unchanged from round 3 for attribution)

template <int KK, bool OUT_BF16>
__global__ __launch_bounds__(1024) void gemm256(
    const u16* __restrict__ A, const u16* __restrict__ Bt,
    const float* __restrict__ bias, void* __restrict__ Cv, int N) {
  constexpr int NT = KK / 64;
  __shared__ u16 smem[65536];  // 2 x [A 256x64 | B 256x64] bf16 = 128 KiB
  const int tid = threadIdx.x;
  const int lane = tid & 63, wid = tid >> 6;   // wid 0..15
  const int nTn = N >> 8;
  const int qx = gridDim.x >> 3;
  const int wg = (blockIdx.x & 7) * qx + (blockIdx.x >> 3);
  const long m0 = (long)(wg / nTn) * 256;
  const long n0 = (long)(wg % nTn) * 256;
  const int wr = wid >> 2, wc = wid & 3;       // 4x4 waves, each 64x64 out
  const int hi = lane >> 4, lo = lane & 15;
  const u16* Ab = A + m0 * KK;
  const u16* Bb = Bt + n0 * KK;
  const int srow_ = tid >> 3;  // 0..127: row within a 128-row staging round
  const int schunk = tid & 7;  // 16B chunk within row

  f32x4 acc[4][4];
#pragma unroll
  for (int mi = 0; mi < 4; ++mi)
#pragma unroll
    for (int ni = 0; ni < 4; ++ni) acc[mi][ni] = f32x4{0.f, 0.f, 0.f, 0.f};

  auto stage = [&](int t) {
    u16* base = &smem[(t & 1) * 32768];
    const int kt = t * 64;
#pragma unroll
    for (int j = 0; j < 2; ++j) {
      int row = j * 128 + srow_;
      int colE = (schunk ^ (row & 7)) << 3;  // inverse-swizzled global source
      gload_lds16(Ab + (long)row * KK + kt + colE, &base[(j * 1024 + tid) * 8]);
    }
#pragma unroll
    for (int j = 0; j < 2; ++j) {
      int row = j * 128 + srow_;
      int colE = (schunk ^ (row & 7)) << 3;
      gload_lds16(Bb + (long)row * KK + kt + colE, &base[16384 + (j * 1024 + tid) * 8]);
    }
  };

  stage(0);
#pragma unroll
  for (int t = 0; t < NT; ++t) {
    if (t + 1 < NT) {
      stage(t + 1);
      asm volatile("s_waitcnt vmcnt(4)" ::: "memory");  // batch t done; batch t+1 in flight
    } else {
      asm volatile("s_waitcnt vmcnt(0)" ::: "memory");
    }
    __builtin_amdgcn_sched_barrier(0);
    __builtin_amdgcn_s_barrier();
    const u16* aB = &smem[(t & 1) * 32768];
    const u16* bB = aB + 16384;
#pragma unroll
    for (int ks = 0; ks < 2; ++ks) {
      const int slot = ((hi + ks * 4) ^ (lo & 7)) << 3;  // swizzled k-chunk
      bf16x8 af[4], bfr[4];
#pragma unroll
      for (int mi = 0; mi < 4; ++mi)
        af[mi] = *(const bf16x8*)&aB[(wr * 64 + mi * 16 + lo) * 64 + slot];
#pragma unroll
      for (int ni = 0; ni < 4; ++ni)
        bfr[ni] = *(const bf16x8*)&bB[(wc * 64 + ni * 16 + lo) * 64 + slot];
#pragma unroll
      for (int mi = 0; mi < 4; ++mi)
#pragma unroll
        for (int ni = 0; ni < 4; ++ni)
          acc[mi][ni] = __builtin_amdgcn_mfma_f32_16x16x32_bf16(af[mi], bfr[ni], acc[mi][ni], 0, 0, 0);
    }
    __builtin_amdgcn_sched_barrier(0);
    __builtin_amdgcn_s_barrier();
  }

  float bb[4];
#pragma unroll
  for (int ni = 0; ni < 4; ++ni) bb[ni] = bias[n0 + wc * 64 + ni * 16 + lo];

  if (OUT_BF16) {
    u16* Cg = (u16*)Cv;
#pragma unroll
    for (int mi = 0; mi < 4; ++mi)
#pragma unroll
      for (int ni = 0; ni < 4; ++ni) {
#pragma unroll
        for (int j = 0; j < 4; ++j) {
          int row = wr * 64 + mi * 16 + hi * 4 + j;
          int chunk = (wc * 8 + ni * 2 + (lo >> 3)) ^ ((row >> 2) & 7);
          smem[row * 256 + chunk * 8 + (lo & 7)] = f2b(acc[mi][ni][j] + bb[ni]);
        }
      }
    __syncthreads();
#pragma unroll
    for (int it = 0; it < 8; ++it) {
      int idx = it * 1024 + tid;
      int row = idx >> 5, c = idx & 31;
      int cs = c ^ ((row >> 2) & 7);
      *(u16x8*)(Cg + (m0 + row) * N + n0 + c * 8) = *(const u16x8*)&smem[row * 256 + cs * 8];
    }
  } else {
    float* Cg = (float*)Cv;
#pragma unroll
    for (int mi = 0; mi < 4; ++mi)
#pragma unroll
      for (int ni = 0; ni < 4; ++ni) {
        long cg = n0 + wc * 64 + ni * 16 + lo;
#pragma unroll
        for (int j = 0; j < 4; ++j)
          Cg[(m0 + wr * 64 + mi * 16 + hi * 4 + j) * N + cg] = acc[mi][ni][j] + bb[ni];
      }
  }
}

// ---------------- axial attention v3: swapped-operand, in-register P ----------------
// One block (4 waves, 256 thr) per (b,w,head). LDS = vt only (16 KB) -> 4 blocks/CU.
// QK^T computed swapped: S^T = mfma(K_frag, Q_frag); both frags load DIRECTLY from
// global (row-major slices). Lane (lo,hi) then holds S[q = wid*32+cg*16+lo]
// [kr = ni*16+hi*4+j]: the softmax row is lane-local across its 4 hi-copies ->
// row reduce = shfl_xor(16) + shfl_xor(32). P is normalized in-register, packed to
// bf16 quads (quad qd = ni*4+hi holds yp = 4*qd..4*qd+3), then a 2-round butterfly
// (xor32, xor16) routes quads so lane (lo,hi) ends with P[q=lo][yp = hi*8+ks*32+0..7]
// = exactly the PV A-frag. Routing (class c = source hi, parity par = ni&1;
// destination hi_t = 2*par + (c>>1)):
//   round1 xor32: h0,h1 send odd-ni ; h2,h3 send even-ni
//   round2 xor16: h0,h3 forward the round-1 recv ; h1,h2 forward their kept half
// Final: setA = lower class of the pair, setB = upper; A-frag(ks) =
//   {setA[ks].pk0, setA[ks].pk1, setB[ks].pk0, setB[ks].pk1}  (ni ordinal = ks).

__global__ __launch_bounds__(256, 4) void attn_axial(const u16* __restrict__ qkv,
                                                     u16* __restrict__ ao) {
  __shared__ u16 vt[8192];  // [64 d][128 yp] chunk-swizzled (16 KB)

  const int g = blockIdx.x;
  const int n = g & 7, w = (g >> 3) & 127, b = g >> 10;
  const int tid = threadIdx.x, lane = tid & 63, wid = tid >> 6;
  const size_t ystr = (size_t)128 * 1536;
  const size_t base = (size_t)(b * 16384 + w) * 1536;
  const size_t bq_ = base + n * 64;
  const size_t bk_ = base + 512 + n * 64;
  const size_t bv_ = base + 1024 + n * 64;
  const int hi = lane >> 4, lo = lane & 15;

  // ---- V -> regs (latency hides under QK^T) ----
  const int vyp = (tid & 63) * 2;
  const u16* vg = qkv + bv_ + (size_t)vyp * ystr + wid * 16;
  u16x8 va0 = *(const u16x8*)vg;
  u16x8 va1 = *(const u16x8*)(vg + 8);
  u16x8 vc0 = *(const u16x8*)(vg + ystr);
  u16x8 vc1 = *(const u16x8*)(vg + ystr + 8);

  // ---- Q B-frags (direct global) ----
  bf16x8 qf[2][2];
#pragma unroll
  for (int cg = 0; cg < 2; ++cg)
#pragma unroll
    for (int ks = 0; ks < 2; ++ks)
      qf[cg][ks] = *(const bf16x8*)(qkv + bq_ +
          (size_t)(wid * 32 + cg * 16 + lo) * ystr + hi * 8 + ks * 32);

  // ---- swapped QK^T: s2[cg][ni] = S^T fragments ----
  f32x4 s2[2][8];
#pragma unroll
  for (int cg = 0; cg < 2; ++cg)
#pragma unroll
    for (int ni = 0; ni < 8; ++ni) s2[cg][ni] = f32x4{0.f, 0.f, 0.f, 0.f};
  __builtin_amdgcn_s_setprio(1);
#pragma unroll
  for (int ks = 0; ks < 2; ++ks)
#pragma unroll
    for (int ni = 0; ni < 8; ++ni) {
      bf16x8 kf = *(const bf16x8*)(qkv + bk_ +
          (size_t)(ni * 16 + lo) * ystr + hi * 8 + ks * 32);
      s2[0][ni] = __builtin_amdgcn_mfma_f32_16x16x32_bf16(kf, qf[0][ks], s2[0][ni], 0, 0, 0);
      s2[1][ni] = __builtin_amdgcn_mfma_f32_16x16x32_bf16(kf, qf[1][ks], s2[1][ni], 0, 0, 0);
    }
  __builtin_amdgcn_s_setprio(0);

  // ---- V transpose -> vt (verbatim-verified v2 write pattern) ----
  {
    unsigned* vt32 = (unsigned*)vt;
    const int cch = vyp >> 3;          // 16B chunk 0..15
    const int cw = (vyp >> 1) & 3;     // dword within chunk
#pragma unroll
    for (int e = 0; e < 8; ++e) {
      const int d0 = wid * 16 + e, d1 = wid * 16 + 8 + e;
      const int c0s = (cch & 8) | ((cch & 7) ^ (d0 & 7));
      const int c1s = (cch & 8) | ((cch & 7) ^ (d1 & 7));
      vt32[d0 * 64 + c0s * 4 + cw] = (unsigned)va0[e] | ((unsigned)vc0[e] << 16);
      vt32[d1 * 64 + c1s * 4 + cw] = (unsigned)va1[e] | ((unsigned)vc1[e] << 16);
    }
  }

  // ---- softmax + pack + butterfly exchange (no LDS) ----
  unsigned setA[2][4][2], setB[2][4][2];
#pragma unroll
  for (int cg = 0; cg < 2; ++cg) {
    float mx = s2[cg][0][0];
#pragma unroll
    for (int ni = 0; ni < 8; ++ni)
#pragma unroll
      for (int j = 0; j < 4; ++j) mx = fmaxf(mx, s2[cg][ni][j]);
    mx = fmaxf(mx, __shfl_xor(mx, 16, 64));
    mx = fmaxf(mx, __shfl_xor(mx, 32, 64));
    float sum = 0.f;
#pragma unroll
    for (int ni = 0; ni < 8; ++ni)
#pragma unroll
      for (int j = 0; j < 4; ++j) {
        float e = exp2f((s2[cg][ni][j] - mx) * 1.44269504f);
        s2[cg][ni][j] = e;
        sum += e;
      }
    sum += __shfl_xor(sum, 16, 64);
    sum += __shfl_xor(sum, 32, 64);
    const float r = 1.f / sum;

    // pack normalized probs into bf16 quads: pkE = even ni (ordinal o: ni=2o), pkO = odd
    unsigned pkE[4][2], pkO[4][2];
#pragma unroll
    for (int o = 0; o < 4; ++o) {
      pkE[o][0] = cvtpk(s2[cg][2 * o][0] * r, s2[cg][2 * o][1] * r);
      pkE[o][1] = cvtpk(s2[cg][2 * o][2] * r, s2[cg][2 * o][3] * r);
      pkO[o][0] = cvtpk(s2[cg][2 * o + 1][0] * r, s2[cg][2 * o + 1][1] * r);
      pkO[o][1] = cvtpk(s2[cg][2 * o + 1][2] * r, s2[cg][2 * o + 1][3] * r);
    }
    // round 1 (xor32): h0,h1 send pkO (keep pkE); h2,h3 send pkE (keep pkO)
    const bool lowHi = (hi < 2);
    unsigned keepR[4][2], gotR[4][2];
#pragma unroll
    for (int o = 0; o < 4; ++o)
#pragma unroll
      for (int e = 0; e < 2; ++e) {
        unsigned snd = lowHi ? pkO[o][e] : pkE[o][e];
        keepR[o][e] = lowHi ? pkE[o][e] : pkO[o][e];
        gotR[o][e] = __shfl_xor(snd, 32, 64);
      }
    // round 2 (xor16): h0,h3 send gotR ; h1,h2 send keepR
    const bool fwdGot = (hi == 0) || (hi == 3);
    unsigned recv2[4][2];
#pragma unroll
    for (int o = 0; o < 4; ++o)
#pragma unroll
      for (int e = 0; e < 2; ++e) {
        unsigned snd = fwdGot ? gotR[o][e] : keepR[o][e];
        recv2[o][e] = __shfl_xor(snd, 16, 64);
      }
    // final selects:
    //   setA (lower class): h0 keepR, h1 recv2, h2 gotR, h3 recv2
    //   setB (upper class): h0 recv2, h1 gotR, h2 recv2, h3 keepR
#pragma unroll
    for (int o = 0; o < 4; ++o)
#pragma unroll
      for (int e = 0; e < 2; ++e) {
        setA[cg][o][e] = (hi & 1) ? recv2[o][e] : (hi == 0 ? keepR[o][e] : gotR[o][e]);
        setB[cg][o][e] = (hi & 1) ? (hi == 1 ? gotR[o][e] : keepR[o][e]) : recv2[o][e];
      }
  }

  __syncthreads();  // vt ready

  // ---- PV: O[q][d] = P @ V  (A-frag from registers, B-frag from vt) ----
  f32x4 o2[2][4];
#pragma unroll
  for (int cg = 0; cg < 2; ++cg)
#pragma unroll
    for (int ni = 0; ni < 4; ++ni) o2[cg][ni] = f32x4{0.f, 0.f, 0.f, 0.f};
  __builtin_amdgcn_s_setprio(1);
#pragma unroll
  for (int ks = 0; ks < 4; ++ks) {
    const int cch = hi + ks * 4;
    bf16x8 pa[2];
#pragma unroll
    for (int cg = 0; cg < 2; ++cg) {
      u32x4 t;
      t[0] = setA[cg][ks][0]; t[1] = setA[cg][ks][1];
      t[2] = setB[cg][ks][0]; t[3] = setB[cg][ks][1];
      pa[cg] = __builtin_bit_cast(bf16x8, t);
    }
#pragma unroll
    for (int ni = 0; ni < 4; ++ni) {
      const int vr = ni * 16 + lo;
      const int cs = (cch & 8) | ((cch & 7) ^ (vr & 7));
      bf16x8 vf = *(const bf16x8*)&vt[vr * 128 + cs * 8];
      o2[0][ni] = __builtin_amdgcn_mfma_f32_16x16x32_bf16(pa[0], vf, o2[0][ni], 0, 0, 0);
      o2[1][ni] = __builtin_amdgcn_mfma_f32_16x16x32_bf16(pa[1], vf, o2[1][ni], 0, 0, 0);
    }
  }
  __builtin_amdgcn_s_setprio(0);

  // ---- store (P already normalized) ----
#pragma unroll
  for (int cg = 0; cg < 2; ++cg)
#pragma unroll
    for (int j = 0; j < 4; ++j) {
      const int q = wid * 32 + cg * 16 + hi * 4 + j;
      const size_t obase = ((size_t)(b * 16384 + q * 128 + w)) * 512 + (size_t)n * 64;
#pragma unroll
      for (int ni = 0; ni < 4; ++ni)
        ao[obase + ni * 16 + lo] = f2b(o2[cg][ni][j]);
    }
}

// ---------------- launch ----------------
// ws: qkv [0,192MiB) | xb [192,224) | weights [224,~226)
// ao (bf16, 64 MB) lives IN d_out; gemm2 runs in-place (each block reads only its
// own 256 rows as bf16 before overwriting them as f32 -> race-free, deterministic).

extern "C" void kernel_launch(void* const* d_in, const int* in_sizes, int n_in,
                              void* d_out, int out_size, void* d_ws, size_t ws_size,
                              hipStream_t stream) {
  (void)in_sizes; (void)n_in; (void)out_size; (void)ws_size;
  const float* x  = (const float*)d_in[0];
  const float* Wq = (const float*)d_in[1];
  const float* bq = (const float*)d_in[2];
  const float* Wk = (const float*)d_in[3];
  const float* bk = (const float*)d_in[4];
  const float* Wv = (const float*)d_in[5];
  const float* bv = (const float*)d_in[6];
  const float* Wo = (const float*)d_in[7];
  const float* bo = (const float*)d_in[8];
  float* out = (float*)d_out;

  char* ws = (char*)d_ws;
  const size_t MiB = (size_t)1 << 20;
  u16* qkv   = (u16*)ws;
  u16* xb    = (u16*)(ws + 192 * MiB);
  u16* wqkvT = (u16*)(ws + 224 * MiB);
  u16* woT   = wqkvT + 1536 * 256;
  float* bqkv = (float*)(woT + 256 * 512);

  prep_x<<<2048, 256, 0, stream>>>(x, xb);
  prep_w<<<512, 256, 0, stream>>>(Wq, Wk, Wv, Wo, bq, bk, bv, wqkvT, woT, bqkv);

  gemm256<256, true><<<1536, 1024, 0, stream>>>(xb, wqkvT, bqkv, qkv, 1536);
  attn_axial<<<4096, 256, 0, stream>>>(qkv, (u16*)out);
  gemm256<512, false><<<256, 1024, 0, stream>>>((const u16*)out, woT, bo, out, 256);
}

// Round 5
// 225.260 us; speedup vs baseline: 1.0869x; 1.0869x over previous
//
#include <hip/hip_runtime.h>

typedef unsigned short u16;
typedef __attribute__((ext_vector_type(8))) short bf16x8;
typedef __attribute__((ext_vector_type(8))) unsigned short u16x8;
typedef __attribute__((ext_vector_type(4))) unsigned u32x4;
typedef __attribute__((ext_vector_type(4))) float f32x4;

#define DEVI static __device__ __forceinline__

DEVI u16 f2b(float f) {
  unsigned u = __builtin_bit_cast(unsigned, f);
  return (u16)((u + 0x7FFFu + ((u >> 16) & 1u)) >> 16);
}

DEVI unsigned cvtpk(float a, float b) {  // lo16 = bf16(a), hi16 = bf16(b)
  unsigned r;
  asm("v_cvt_pk_bf16_f32 %0, %1, %2" : "=v"(r) : "v"(a), "v"(b));
  return r;
}

DEVI void gload_lds16(const void* g, void* l) {
  __builtin_amdgcn_global_load_lds(
      (const __attribute__((address_space(1))) unsigned int*)g,
      (__attribute__((address_space(3))) unsigned int*)l, 16, 0, 0);
}

// ---------------- prep kernels ----------------

__global__ __launch_bounds__(256) void prep_x(const float* __restrict__ x, u16* __restrict__ xb) {
  const int n8 = 65536 * 256 / 8;
  int i = blockIdx.x * blockDim.x + threadIdx.x;
  for (; i < n8; i += gridDim.x * blockDim.x) {
    const float4* p = (const float4*)x + (size_t)i * 2;
    float4 a = p[0], b = p[1];
    u16x8 r;
    r[0] = f2b(a.x); r[1] = f2b(a.y); r[2] = f2b(a.z); r[3] = f2b(a.w);
    r[4] = f2b(b.x); r[5] = f2b(b.y); r[6] = f2b(b.z); r[7] = f2b(b.w);
    *(u16x8*)(xb + (size_t)i * 8) = r;
  }
}

// wqkvT[1536][256]: row n<512 -> Wq[:,n]*0.125 ; 512..1023 -> Wk ; 1024.. -> Wv
// woT[256][512]: row n -> Wo[:,n] ;  bqkv[1536] = concat(bq*0.125, bk, bv)
__global__ __launch_bounds__(256) void prep_w(
    const float* __restrict__ Wq, const float* __restrict__ Wk,
    const float* __restrict__ Wv, const float* __restrict__ Wo,
    const float* __restrict__ bq, const float* __restrict__ bk, const float* __restrict__ bv,
    u16* __restrict__ wqkvT, u16* __restrict__ woT, float* __restrict__ bqkv) {
  const int NW1 = 1536 * 256, NW2 = 256 * 512;
  const int total = NW1 + NW2 + 1536;
  int i = blockIdx.x * blockDim.x + threadIdx.x;
  for (; i < total; i += gridDim.x * blockDim.x) {
    if (i < NW1) {
      int nn = i >> 8, kk = i & 255;
      float v;
      if (nn < 512)       v = Wq[kk * 512 + nn] * 0.125f;
      else if (nn < 1024) v = Wk[kk * 512 + (nn - 512)];
      else                v = Wv[kk * 512 + (nn - 1024)];
      wqkvT[i] = f2b(v);
    } else if (i < NW1 + NW2) {
      int j = i - NW1;
      int nn = j >> 9, kk = j & 511;
      woT[j] = f2b(Wo[kk * 256 + nn]);
    } else {
      int j = i - NW1 - NW2;
      bqkv[j] = (j < 512) ? bq[j] * 0.125f : (j < 1024 ? bk[j - 512] : bv[j - 1024]);
    }
  }
}

// ---------------- GEMM: C[M,N] = A[M,K](bf16) * Bt[N,K]^T(bf16) + bias ----------------
// (unchanged for attribution)

template <int KK, bool OUT_BF16>
__global__ __launch_bounds__(1024) void gemm256(
    const u16* __restrict__ A, const u16* __restrict__ Bt,
    const float* __restrict__ bias, void* __restrict__ Cv, int N) {
  constexpr int NT = KK / 64;
  __shared__ u16 smem[65536];  // 2 x [A 256x64 | B 256x64] bf16 = 128 KiB
  const int tid = threadIdx.x;
  const int lane = tid & 63, wid = tid >> 6;   // wid 0..15
  const int nTn = N >> 8;
  const int qx = gridDim.x >> 3;
  const int wg = (blockIdx.x & 7) * qx + (blockIdx.x >> 3);
  const long m0 = (long)(wg / nTn) * 256;
  const long n0 = (long)(wg % nTn) * 256;
  const int wr = wid >> 2, wc = wid & 3;       // 4x4 waves, each 64x64 out
  const int hi = lane >> 4, lo = lane & 15;
  const u16* Ab = A + m0 * KK;
  const u16* Bb = Bt + n0 * KK;
  const int srow_ = tid >> 3;  // 0..127: row within a 128-row staging round
  const int schunk = tid & 7;  // 16B chunk within row

  f32x4 acc[4][4];
#pragma unroll
  for (int mi = 0; mi < 4; ++mi)
#pragma unroll
    for (int ni = 0; ni < 4; ++ni) acc[mi][ni] = f32x4{0.f, 0.f, 0.f, 0.f};

  auto stage = [&](int t) {
    u16* base = &smem[(t & 1) * 32768];
    const int kt = t * 64;
#pragma unroll
    for (int j = 0; j < 2; ++j) {
      int row = j * 128 + srow_;
      int colE = (schunk ^ (row & 7)) << 3;  // inverse-swizzled global source
      gload_lds16(Ab + (long)row * KK + kt + colE, &base[(j * 1024 + tid) * 8]);
    }
#pragma unroll
    for (int j = 0; j < 2; ++j) {
      int row = j * 128 + srow_;
      int colE = (schunk ^ (row & 7)) << 3;
      gload_lds16(Bb + (long)row * KK + kt + colE, &base[16384 + (j * 1024 + tid) * 8]);
    }
  };

  stage(0);
#pragma unroll
  for (int t = 0; t < NT; ++t) {
    if (t + 1 < NT) {
      stage(t + 1);
      asm volatile("s_waitcnt vmcnt(4)" ::: "memory");  // batch t done; batch t+1 in flight
    } else {
      asm volatile("s_waitcnt vmcnt(0)" ::: "memory");
    }
    __builtin_amdgcn_sched_barrier(0);
    __builtin_amdgcn_s_barrier();
    const u16* aB = &smem[(t & 1) * 32768];
    const u16* bB = aB + 16384;
#pragma unroll
    for (int ks = 0; ks < 2; ++ks) {
      const int slot = ((hi + ks * 4) ^ (lo & 7)) << 3;  // swizzled k-chunk
      bf16x8 af[4], bfr[4];
#pragma unroll
      for (int mi = 0; mi < 4; ++mi)
        af[mi] = *(const bf16x8*)&aB[(wr * 64 + mi * 16 + lo) * 64 + slot];
#pragma unroll
      for (int ni = 0; ni < 4; ++ni)
        bfr[ni] = *(const bf16x8*)&bB[(wc * 64 + ni * 16 + lo) * 64 + slot];
#pragma unroll
      for (int mi = 0; mi < 4; ++mi)
#pragma unroll
        for (int ni = 0; ni < 4; ++ni)
          acc[mi][ni] = __builtin_amdgcn_mfma_f32_16x16x32_bf16(af[mi], bfr[ni], acc[mi][ni], 0, 0, 0);
    }
    __builtin_amdgcn_sched_barrier(0);
    __builtin_amdgcn_s_barrier();
  }

  float bb[4];
#pragma unroll
  for (int ni = 0; ni < 4; ++ni) bb[ni] = bias[n0 + wc * 64 + ni * 16 + lo];

  if (OUT_BF16) {
    u16* Cg = (u16*)Cv;
#pragma unroll
    for (int mi = 0; mi < 4; ++mi)
#pragma unroll
      for (int ni = 0; ni < 4; ++ni) {
#pragma unroll
        for (int j = 0; j < 4; ++j) {
          int row = wr * 64 + mi * 16 + hi * 4 + j;
          int chunk = (wc * 8 + ni * 2 + (lo >> 3)) ^ ((row >> 2) & 7);
          smem[row * 256 + chunk * 8 + (lo & 7)] = f2b(acc[mi][ni][j] + bb[ni]);
        }
      }
    __syncthreads();
#pragma unroll
    for (int it = 0; it < 8; ++it) {
      int idx = it * 1024 + tid;
      int row = idx >> 5, c = idx & 31;
      int cs = c ^ ((row >> 2) & 7);
      *(u16x8*)(Cg + (m0 + row) * N + n0 + c * 8) = *(const u16x8*)&smem[row * 256 + cs * 8];
    }
  } else {
    float* Cg = (float*)Cv;
#pragma unroll
    for (int mi = 0; mi < 4; ++mi)
#pragma unroll
      for (int ni = 0; ni < 4; ++ni) {
        long cg = n0 + wc * 64 + ni * 16 + lo;
#pragma unroll
        for (int j = 0; j < 4; ++j)
          Cg[(m0 + wr * 64 + mi * 16 + hi * 4 + j) * N + cg] = acc[mi][ni][j] + bb[ni];
      }
  }
}

// ---------------- axial attention v4: LDS-staged K + swapped QK^T + in-reg P ----------------
// One block (4 waves, 256 thr) per (b,w,head). LDS 32 KB: kld [128][64] + vt [64][128].
// K staged ONCE via global_load_lds (linear dest, source chunk^(row&7) pre-swizzled)
// and broadcast-read by all 4 waves (v3's per-wave scattered global K reads were the
// latency bound: MfmaUtil 6%, VGPR 60 -> serialized L2 chains). Q direct to regs
// (4 independent 16B loads, issued up-front). V -> regs -> swizzled vt (proven v2/v3).
// ONE barrier total. Softmax + P stay in-register (v3's butterfly, proven).

__global__ __launch_bounds__(256, 4) void attn_axial(const u16* __restrict__ qkv,
                                                     u16* __restrict__ ao) {
  __shared__ u16 smem[16384];    // 32 KB
  u16* kld = smem;               // [128][64]  chunk^(row&7) swizzled
  u16* vt  = smem + 8192;        // [64 d][128 yp] chunk-swizzled

  const int g = blockIdx.x;
  const int n = g & 7, w = (g >> 3) & 127, b = g >> 10;
  const int tid = threadIdx.x, lane = tid & 63, wid = tid >> 6;
  const size_t ystr = (size_t)128 * 1536;
  const size_t base = (size_t)(b * 16384 + w) * 1536;
  const size_t bq_ = base + n * 64;
  const size_t bk_ = base + 512 + n * 64;
  const size_t bv_ = base + 1024 + n * 64;
  const int hi = lane >> 4, lo = lane & 15;

  // ---- K: global -> LDS (cooperative, once per block) ----
  {
    const int kr0 = tid >> 3, kc = tid & 7;
#pragma unroll
    for (int i = 0; i < 4; ++i) {
      const int row = i * 32 + kr0;
      const int srcC = (kc ^ (row & 7)) << 3;  // inverse-swizzled global source
      gload_lds16(qkv + bk_ + (size_t)row * ystr + srcC, &kld[(i * 256 + tid) * 8]);
    }
  }

  // ---- V -> regs (latency hides under staging) ----
  const int vyp = (tid & 63) * 2;
  const u16* vg = qkv + bv_ + (size_t)vyp * ystr + wid * 16;
  u16x8 va0 = *(const u16x8*)vg;
  u16x8 va1 = *(const u16x8*)(vg + 8);
  u16x8 vc0 = *(const u16x8*)(vg + ystr);
  u16x8 vc1 = *(const u16x8*)(vg + ystr + 8);

  // ---- Q B-frags (direct global, 4 independent loads) ----
  bf16x8 qf[2][2];
#pragma unroll
  for (int cg = 0; cg < 2; ++cg)
#pragma unroll
    for (int ks = 0; ks < 2; ++ks)
      qf[cg][ks] = *(const bf16x8*)(qkv + bq_ +
          (size_t)(wid * 32 + cg * 16 + lo) * ystr + hi * 8 + ks * 32);

  // ---- V transpose -> vt (verbatim-verified write pattern) ----
  {
    unsigned* vt32 = (unsigned*)vt;
    const int cch = vyp >> 3;          // 16B chunk 0..15
    const int cw = (vyp >> 1) & 3;     // dword within chunk
#pragma unroll
    for (int e = 0; e < 8; ++e) {
      const int d0 = wid * 16 + e, d1 = wid * 16 + 8 + e;
      const int c0s = (cch & 8) | ((cch & 7) ^ (d0 & 7));
      const int c1s = (cch & 8) | ((cch & 7) ^ (d1 & 7));
      vt32[d0 * 64 + c0s * 4 + cw] = (unsigned)va0[e] | ((unsigned)vc0[e] << 16);
      vt32[d1 * 64 + c1s * 4 + cw] = (unsigned)va1[e] | ((unsigned)vc1[e] << 16);
    }
  }

  __syncthreads();  // kld (vmcnt) + vt (lgkm) complete; the ONLY barrier

  // ---- swapped QK^T: s2[cg][ni] = S^T fragments (K from LDS, broadcast) ----
  f32x4 s2[2][8];
#pragma unroll
  for (int cg = 0; cg < 2; ++cg)
#pragma unroll
    for (int ni = 0; ni < 8; ++ni) s2[cg][ni] = f32x4{0.f, 0.f, 0.f, 0.f};
  __builtin_amdgcn_s_setprio(1);
#pragma unroll
  for (int ks = 0; ks < 2; ++ks)
#pragma unroll
    for (int ni = 0; ni < 8; ++ni) {
      const int kr = ni * 16 + lo;
      bf16x8 kf = *(const bf16x8*)&kld[kr * 64 + (((hi + ks * 4) ^ (kr & 7)) << 3)];
      s2[0][ni] = __builtin_amdgcn_mfma_f32_16x16x32_bf16(kf, qf[0][ks], s2[0][ni], 0, 0, 0);
      s2[1][ni] = __builtin_amdgcn_mfma_f32_16x16x32_bf16(kf, qf[1][ks], s2[1][ni], 0, 0, 0);
    }
  __builtin_amdgcn_s_setprio(0);

  // ---- softmax + pack + butterfly exchange (no LDS; proven in v3) ----
  unsigned setA[2][4][2], setB[2][4][2];
#pragma unroll
  for (int cg = 0; cg < 2; ++cg) {
    float mx = s2[cg][0][0];
#pragma unroll
    for (int ni = 0; ni < 8; ++ni)
#pragma unroll
      for (int j = 0; j < 4; ++j) mx = fmaxf(mx, s2[cg][ni][j]);
    mx = fmaxf(mx, __shfl_xor(mx, 16, 64));
    mx = fmaxf(mx, __shfl_xor(mx, 32, 64));
    float sum = 0.f;
#pragma unroll
    for (int ni = 0; ni < 8; ++ni)
#pragma unroll
      for (int j = 0; j < 4; ++j) {
        float e = exp2f((s2[cg][ni][j] - mx) * 1.44269504f);
        s2[cg][ni][j] = e;
        sum += e;
      }
    sum += __shfl_xor(sum, 16, 64);
    sum += __shfl_xor(sum, 32, 64);
    const float r = 1.f / sum;

    unsigned pkE[4][2], pkO[4][2];
#pragma unroll
    for (int o = 0; o < 4; ++o) {
      pkE[o][0] = cvtpk(s2[cg][2 * o][0] * r, s2[cg][2 * o][1] * r);
      pkE[o][1] = cvtpk(s2[cg][2 * o][2] * r, s2[cg][2 * o][3] * r);
      pkO[o][0] = cvtpk(s2[cg][2 * o + 1][0] * r, s2[cg][2 * o + 1][1] * r);
      pkO[o][1] = cvtpk(s2[cg][2 * o + 1][2] * r, s2[cg][2 * o + 1][3] * r);
    }
    // round 1 (xor32): h0,h1 send pkO (keep pkE); h2,h3 send pkE (keep pkO)
    const bool lowHi = (hi < 2);
    unsigned keepR[4][2], gotR[4][2];
#pragma unroll
    for (int o = 0; o < 4; ++o)
#pragma unroll
      for (int e = 0; e < 2; ++e) {
        unsigned snd = lowHi ? pkO[o][e] : pkE[o][e];
        keepR[o][e] = lowHi ? pkE[o][e] : pkO[o][e];
        gotR[o][e] = __shfl_xor(snd, 32, 64);
      }
    // round 2 (xor16): h0,h3 send gotR ; h1,h2 send keepR
    const bool fwdGot = (hi == 0) || (hi == 3);
    unsigned recv2[4][2];
#pragma unroll
    for (int o = 0; o < 4; ++o)
#pragma unroll
      for (int e = 0; e < 2; ++e) {
        unsigned snd = fwdGot ? gotR[o][e] : keepR[o][e];
        recv2[o][e] = __shfl_xor(snd, 16, 64);
      }
    //   setA (lower class): h0 keepR, h1 recv2, h2 gotR, h3 recv2
    //   setB (upper class): h0 recv2, h1 gotR, h2 recv2, h3 keepR
#pragma unroll
    for (int o = 0; o < 4; ++o)
#pragma unroll
      for (int e = 0; e < 2; ++e) {
        setA[cg][o][e] = (hi & 1) ? recv2[o][e] : (hi == 0 ? keepR[o][e] : gotR[o][e]);
        setB[cg][o][e] = (hi & 1) ? (hi == 1 ? gotR[o][e] : keepR[o][e]) : recv2[o][e];
      }
  }

  // ---- PV: O[q][d] = P @ V  (A-frag from registers, B-frag from vt) ----
  f32x4 o2[2][4];
#pragma unroll
  for (int cg = 0; cg < 2; ++cg)
#pragma unroll
    for (int ni = 0; ni < 4; ++ni) o2[cg][ni] = f32x4{0.f, 0.f, 0.f, 0.f};
  __builtin_amdgcn_s_setprio(1);
#pragma unroll
  for (int ks = 0; ks < 4; ++ks) {
    const int cch = hi + ks * 4;
    bf16x8 pa[2];
#pragma unroll
    for (int cg = 0; cg < 2; ++cg) {
      u32x4 t;
      t[0] = setA[cg][ks][0]; t[1] = setA[cg][ks][1];
      t[2] = setB[cg][ks][0]; t[3] = setB[cg][ks][1];
      pa[cg] = __builtin_bit_cast(bf16x8, t);
    }
#pragma unroll
    for (int ni = 0; ni < 4; ++ni) {
      const int vr = ni * 16 + lo;
      const int cs = (cch & 8) | ((cch & 7) ^ (vr & 7));
      bf16x8 vf = *(const bf16x8*)&vt[vr * 128 + cs * 8];
      o2[0][ni] = __builtin_amdgcn_mfma_f32_16x16x32_bf16(pa[0], vf, o2[0][ni], 0, 0, 0);
      o2[1][ni] = __builtin_amdgcn_mfma_f32_16x16x32_bf16(pa[1], vf, o2[1][ni], 0, 0, 0);
    }
  }
  __builtin_amdgcn_s_setprio(0);

  // ---- store (P already normalized) ----
#pragma unroll
  for (int cg = 0; cg < 2; ++cg)
#pragma unroll
    for (int j = 0; j < 4; ++j) {
      const int q = wid * 32 + cg * 16 + hi * 4 + j;
      const size_t obase = ((size_t)(b * 16384 + q * 128 + w)) * 512 + (size_t)n * 64;
#pragma unroll
      for (int ni = 0; ni < 4; ++ni)
        ao[obase + ni * 16 + lo] = f2b(o2[cg][ni][j]);
    }
}

// ---------------- launch ----------------
// ws: qkv [0,192MiB) | xb [192,224) | weights [224,~226)
// ao (bf16, 64 MB) lives IN d_out; gemm2 runs in-place (each block reads only its
// own 256 rows as bf16 before overwriting them as f32 -> race-free, deterministic).

extern "C" void kernel_launch(void* const* d_in, const int* in_sizes, int n_in,
                              void* d_out, int out_size, void* d_ws, size_t ws_size,
                              hipStream_t stream) {
  (void)in_sizes; (void)n_in; (void)out_size; (void)ws_size;
  const float* x  = (const float*)d_in[0];
  const float* Wq = (const float*)d_in[1];
  const float* bq = (const float*)d_in[2];
  const float* Wk = (const float*)d_in[3];
  const float* bk = (const float*)d_in[4];
  const float* Wv = (const float*)d_in[5];
  const float* bv = (const float*)d_in[6];
  const float* Wo = (const float*)d_in[7];
  const float* bo = (const float*)d_in[8];
  float* out = (float*)d_out;

  char* ws = (char*)d_ws;
  const size_t MiB = (size_t)1 << 20;
  u16* qkv   = (u16*)ws;
  u16* xb    = (u16*)(ws + 192 * MiB);
  u16* wqkvT = (u16*)(ws + 224 * MiB);
  u16* woT   = wqkvT + 1536 * 256;
  float* bqkv = (float*)(woT + 256 * 512);

  prep_x<<<2048, 256, 0, stream>>>(x, xb);
  prep_w<<<512, 256, 0, stream>>>(Wq, Wk, Wv, Wo, bq, bk, bv, wqkvT, woT, bqkv);

  gemm256<256, true><<<1536, 1024, 0, stream>>>(xb, wqkvT, bqkv, qkv, 1536);
  attn_axial<<<4096, 256, 0, stream>>>(qkv, (u16*)out);
  gemm256<512, false><<<256, 1024, 0, stream>>>((const u16*)out, woT, bo, out, 256);
}

// Round 6
// 210.372 us; speedup vs baseline: 1.1639x; 1.0708x over previous
//
#include <hip/hip_runtime.h>

typedef unsigned short u16;
typedef __attribute__((ext_vector_type(8))) short bf16x8;
typedef __attribute__((ext_vector_type(8))) unsigned short u16x8;
typedef __attribute__((ext_vector_type(4))) unsigned u32x4;
typedef __attribute__((ext_vector_type(4))) float f32x4;

#define DEVI static __device__ __forceinline__

DEVI u16 f2b(float f) {
  unsigned u = __builtin_bit_cast(unsigned, f);
  return (u16)((u + 0x7FFFu + ((u >> 16) & 1u)) >> 16);
}

DEVI unsigned cvtpk(float a, float b) {  // lo16 = bf16(a), hi16 = bf16(b)
  unsigned r;
  asm("v_cvt_pk_bf16_f32 %0, %1, %2" : "=v"(r) : "v"(a), "v"(b));
  return r;
}

DEVI void gload_lds16(const void* g, void* l) {
  __builtin_amdgcn_global_load_lds(
      (const __attribute__((address_space(1))) unsigned int*)g,
      (__attribute__((address_space(3))) unsigned int*)l, 16, 0, 0);
}

// ---------------- prep kernels ----------------

__global__ __launch_bounds__(256) void prep_x(const float* __restrict__ x, u16* __restrict__ xb) {
  const int n8 = 65536 * 256 / 8;
  int i = blockIdx.x * blockDim.x + threadIdx.x;
  for (; i < n8; i += gridDim.x * blockDim.x) {
    const float4* p = (const float4*)x + (size_t)i * 2;
    float4 a = p[0], b = p[1];
    u16x8 r;
    r[0] = f2b(a.x); r[1] = f2b(a.y); r[2] = f2b(a.z); r[3] = f2b(a.w);
    r[4] = f2b(b.x); r[5] = f2b(b.y); r[6] = f2b(b.z); r[7] = f2b(b.w);
    *(u16x8*)(xb + (size_t)i * 8) = r;
  }
}

// wqkvT[1536][256]: row n<512 -> Wq[:,n]*0.125 ; 512..1023 -> Wk ; 1024.. -> Wv
// woT[256][512]: row n -> Wo[:,n] ;  bqkv[1536] = concat(bq*0.125, bk, bv)
__global__ __launch_bounds__(256) void prep_w(
    const float* __restrict__ Wq, const float* __restrict__ Wk,
    const float* __restrict__ Wv, const float* __restrict__ Wo,
    const float* __restrict__ bq, const float* __restrict__ bk, const float* __restrict__ bv,
    u16* __restrict__ wqkvT, u16* __restrict__ woT, float* __restrict__ bqkv) {
  const int NW1 = 1536 * 256, NW2 = 256 * 512;
  const int total = NW1 + NW2 + 1536;
  int i = blockIdx.x * blockDim.x + threadIdx.x;
  for (; i < total; i += gridDim.x * blockDim.x) {
    if (i < NW1) {
      int nn = i >> 8, kk = i & 255;
      float v;
      if (nn < 512)       v = Wq[kk * 512 + nn] * 0.125f;
      else if (nn < 1024) v = Wk[kk * 512 + (nn - 512)];
      else                v = Wv[kk * 512 + (nn - 1024)];
      wqkvT[i] = f2b(v);
    } else if (i < NW1 + NW2) {
      int j = i - NW1;
      int nn = j >> 9, kk = j & 511;
      woT[j] = f2b(Wo[kk * 256 + nn]);
    } else {
      int j = i - NW1 - NW2;
      bqkv[j] = (j < 512) ? bq[j] * 0.125f : (j < 1024 ? bk[j - 512] : bv[j - 1024]);
    }
  }
}

// ---------------- GEMM: C[M,N] = A[M,K](bf16) * Bt[N,K]^T(bf16) + bias ----------------
// 256x256 tile, BK=64, 16 waves (4M x 4N). OMODE: 0 = f32 rows, 2 = bf16 PANELS
// (qkv[((b*128+w)*8+h)*3+t][y][64] so each attn block's working set is one
// contiguous 48 KB -- kills the 384-KB-stride scatter that latency-bound attn).

template <int KK, int OMODE>
__global__ __launch_bounds__(1024) void gemm256(
    const u16* __restrict__ A, const u16* __restrict__ Bt,
    const float* __restrict__ bias, void* __restrict__ Cv, int N) {
  constexpr int NT = KK / 64;
  __shared__ u16 smem[65536];  // 2 x [A 256x64 | B 256x64] bf16 = 128 KiB
  const int tid = threadIdx.x;
  const int lane = tid & 63, wid = tid >> 6;   // wid 0..15
  const int nTn = N >> 8;
  const int qx = gridDim.x >> 3;
  const int wg = (blockIdx.x & 7) * qx + (blockIdx.x >> 3);
  const long m0 = (long)(wg / nTn) * 256;
  const long n0 = (long)(wg % nTn) * 256;
  const int wr = wid >> 2, wc = wid & 3;       // 4x4 waves, each 64x64 out
  const int hi = lane >> 4, lo = lane & 15;
  const u16* Ab = A + m0 * KK;
  const u16* Bb = Bt + n0 * KK;
  const int srow_ = tid >> 3;  // 0..127: row within a 128-row staging round
  const int schunk = tid & 7;  // 16B chunk within row

  f32x4 acc[4][4];
#pragma unroll
  for (int mi = 0; mi < 4; ++mi)
#pragma unroll
    for (int ni = 0; ni < 4; ++ni) acc[mi][ni] = f32x4{0.f, 0.f, 0.f, 0.f};

  auto stage = [&](int t) {
    u16* base = &smem[(t & 1) * 32768];
    const int kt = t * 64;
#pragma unroll
    for (int j = 0; j < 2; ++j) {
      int row = j * 128 + srow_;
      int colE = (schunk ^ (row & 7)) << 3;  // inverse-swizzled global source
      gload_lds16(Ab + (long)row * KK + kt + colE, &base[(j * 1024 + tid) * 8]);
    }
#pragma unroll
    for (int j = 0; j < 2; ++j) {
      int row = j * 128 + srow_;
      int colE = (schunk ^ (row & 7)) << 3;
      gload_lds16(Bb + (long)row * KK + kt + colE, &base[16384 + (j * 1024 + tid) * 8]);
    }
  };

  stage(0);
#pragma unroll
  for (int t = 0; t < NT; ++t) {
    if (t + 1 < NT) {
      stage(t + 1);
      asm volatile("s_waitcnt vmcnt(4)" ::: "memory");  // batch t done; batch t+1 in flight
    } else {
      asm volatile("s_waitcnt vmcnt(0)" ::: "memory");
    }
    __builtin_amdgcn_sched_barrier(0);
    __builtin_amdgcn_s_barrier();
    const u16* aB = &smem[(t & 1) * 32768];
    const u16* bB = aB + 16384;
#pragma unroll
    for (int ks = 0; ks < 2; ++ks) {
      const int slot = ((hi + ks * 4) ^ (lo & 7)) << 3;  // swizzled k-chunk
      bf16x8 af[4], bfr[4];
#pragma unroll
      for (int mi = 0; mi < 4; ++mi)
        af[mi] = *(const bf16x8*)&aB[(wr * 64 + mi * 16 + lo) * 64 + slot];
#pragma unroll
      for (int ni = 0; ni < 4; ++ni)
        bfr[ni] = *(const bf16x8*)&bB[(wc * 64 + ni * 16 + lo) * 64 + slot];
#pragma unroll
      for (int mi = 0; mi < 4; ++mi)
#pragma unroll
        for (int ni = 0; ni < 4; ++ni)
          acc[mi][ni] = __builtin_amdgcn_mfma_f32_16x16x32_bf16(af[mi], bfr[ni], acc[mi][ni], 0, 0, 0);
    }
    __builtin_amdgcn_sched_barrier(0);
    __builtin_amdgcn_s_barrier();
  }

  float bb[4];
#pragma unroll
  for (int ni = 0; ni < 4; ++ni) bb[ni] = bias[n0 + wc * 64 + ni * 16 + lo];

  if (OMODE == 2) {
    // bf16 panel epilogue: stage full 256x256 tile in smem, then store to panels.
    u16* Cg = (u16*)Cv;
#pragma unroll
    for (int mi = 0; mi < 4; ++mi)
#pragma unroll
      for (int ni = 0; ni < 4; ++ni) {
#pragma unroll
        for (int j = 0; j < 4; ++j) {
          int row = wr * 64 + mi * 16 + hi * 4 + j;
          int chunk = (wc * 8 + ni * 2 + (lo >> 3)) ^ ((row >> 2) & 7);
          smem[row * 256 + chunk * 8 + (lo & 7)] = f2b(acc[mi][ni][j] + bb[ni]);
        }
      }
    __syncthreads();
#pragma unroll
    for (int it = 0; it < 8; ++it) {
      int idx = it * 1024 + tid;
      int row = idx >> 5, c = idx & 31;
      int cs = c ^ ((row >> 2) & 7);
      long m = m0 + row;
      int col = (int)n0 + c * 8;
      int b_ = (int)(m >> 14), yw = (int)m & 16383;
      int y = yw >> 7, w = yw & 127;
      int t = col >> 9, h = (col >> 6) & 7, dh = col & 63;
      size_t dst = ((((size_t)(b_ * 128 + w) * 8 + h) * 3 + t) * 128 + y) * 64 + dh;
      *(u16x8*)(Cg + dst) = *(const u16x8*)&smem[row * 256 + cs * 8];
    }
  } else {
    float* Cg = (float*)Cv;
#pragma unroll
    for (int mi = 0; mi < 4; ++mi)
#pragma unroll
      for (int ni = 0; ni < 4; ++ni) {
        long cg = n0 + wc * 64 + ni * 16 + lo;
#pragma unroll
        for (int j = 0; j < 4; ++j)
          Cg[(m0 + wr * 64 + mi * 16 + hi * 4 + j) * N + cg] = acc[mi][ni][j] + bb[ni];
      }
  }
}

// ---------------- axial attention v5: panel layout + v4 dataflow ----------------
// One block (4 waves, 256 thr) per (b,w,head). qkv panels: Q at pq, K at pq+8192,
// V at pq+16384, each [128 y][64 dh] row-major CONTIGUOUS 16 KB -> every load is
// streaming (K-stage: 1 KB contiguous per wave-instr; Q: 16 fully-consumed lines).
// LDS 32 KB: kld [128][64] chunk^(row&7) + vt [64 d][128 y] chunk-swizzled.
// ONE barrier. Softmax + P fully in-register (v3/v4 butterfly, proven).

__global__ __launch_bounds__(256, 5) void attn_axial(const u16* __restrict__ qkv,
                                                     u16* __restrict__ ao) {
  __shared__ u16 smem[16384];    // 32 KB
  u16* kld = smem;               // [128][64]  chunk^(row&7) swizzled
  u16* vt  = smem + 8192;        // [64 d][128 yp] chunk-swizzled

  const int g = blockIdx.x;
  const int n = g & 7, w = (g >> 3) & 127, b = g >> 10;
  const int tid = threadIdx.x, lane = tid & 63, wid = tid >> 6;
  const size_t pq = (((size_t)(b * 128 + w) * 8 + n) * 3) * 8192;
  const u16* Qp = qkv + pq;
  const u16* Kp = qkv + pq + 8192;
  const u16* Vp = qkv + pq + 16384;
  const int hi = lane >> 4, lo = lane & 15;

  // ---- K: global -> LDS (contiguous 1 KB per wave-instr) ----
  {
    const int kr0 = tid >> 3, kc = tid & 7;
#pragma unroll
    for (int i = 0; i < 4; ++i) {
      const int row = i * 32 + kr0;
      const int srcC = (kc ^ (row & 7)) << 3;  // inverse-swizzled source within row
      gload_lds16(Kp + row * 64 + srcC, &kld[(i * 256 + tid) * 8]);
    }
  }

  // ---- V -> regs (row stride now 128 B; lines shared across waves) ----
  const int vyp = (tid & 63) * 2;
  const u16* vg = Vp + vyp * 64 + wid * 16;
  u16x8 va0 = *(const u16x8*)vg;
  u16x8 va1 = *(const u16x8*)(vg + 8);
  u16x8 vc0 = *(const u16x8*)(vg + 64);
  u16x8 vc1 = *(const u16x8*)(vg + 72);

  // ---- Q B-frags (direct global, 4 independent loads, full-line consumption) ----
  bf16x8 qf[2][2];
#pragma unroll
  for (int cg = 0; cg < 2; ++cg)
#pragma unroll
    for (int ks = 0; ks < 2; ++ks)
      qf[cg][ks] = *(const bf16x8*)(Qp + (wid * 32 + cg * 16 + lo) * 64 + hi * 8 + ks * 32);

  // ---- V transpose -> vt (verbatim-verified write pattern) ----
  {
    unsigned* vt32 = (unsigned*)vt;
    const int cch = vyp >> 3;          // 16B chunk 0..15
    const int cw = (vyp >> 1) & 3;     // dword within chunk
#pragma unroll
    for (int e = 0; e < 8; ++e) {
      const int d0 = wid * 16 + e, d1 = wid * 16 + 8 + e;
      const int c0s = (cch & 8) | ((cch & 7) ^ (d0 & 7));
      const int c1s = (cch & 8) | ((cch & 7) ^ (d1 & 7));
      vt32[d0 * 64 + c0s * 4 + cw] = (unsigned)va0[e] | ((unsigned)vc0[e] << 16);
      vt32[d1 * 64 + c1s * 4 + cw] = (unsigned)va1[e] | ((unsigned)vc1[e] << 16);
    }
  }

  __syncthreads();  // kld (vmcnt) + vt (lgkm) complete; the ONLY barrier

  // ---- swapped QK^T: s2[cg][ni] = S^T fragments (K from LDS, broadcast) ----
  f32x4 s2[2][8];
#pragma unroll
  for (int cg = 0; cg < 2; ++cg)
#pragma unroll
    for (int ni = 0; ni < 8; ++ni) s2[cg][ni] = f32x4{0.f, 0.f, 0.f, 0.f};
  __builtin_amdgcn_s_setprio(1);
#pragma unroll
  for (int ks = 0; ks < 2; ++ks)
#pragma unroll
    for (int ni = 0; ni < 8; ++ni) {
      const int kr = ni * 16 + lo;
      bf16x8 kf = *(const bf16x8*)&kld[kr * 64 + (((hi + ks * 4) ^ (kr & 7)) << 3)];
      s2[0][ni] = __builtin_amdgcn_mfma_f32_16x16x32_bf16(kf, qf[0][ks], s2[0][ni], 0, 0, 0);
      s2[1][ni] = __builtin_amdgcn_mfma_f32_16x16x32_bf16(kf, qf[1][ks], s2[1][ni], 0, 0, 0);
    }
  __builtin_amdgcn_s_setprio(0);

  // ---- softmax + pack + butterfly exchange (no LDS; proven in v3/v4) ----
  unsigned setA[2][4][2], setB[2][4][2];
#pragma unroll
  for (int cg = 0; cg < 2; ++cg) {
    float mx = s2[cg][0][0];
#pragma unroll
    for (int ni = 0; ni < 8; ++ni)
#pragma unroll
      for (int j = 0; j < 4; ++j) mx = fmaxf(mx, s2[cg][ni][j]);
    mx = fmaxf(mx, __shfl_xor(mx, 16, 64));
    mx = fmaxf(mx, __shfl_xor(mx, 32, 64));
    float sum = 0.f;
#pragma unroll
    for (int ni = 0; ni < 8; ++ni)
#pragma unroll
      for (int j = 0; j < 4; ++j) {
        float e = exp2f((s2[cg][ni][j] - mx) * 1.44269504f);
        s2[cg][ni][j] = e;
        sum += e;
      }
    sum += __shfl_xor(sum, 16, 64);
    sum += __shfl_xor(sum, 32, 64);
    const float r = 1.f / sum;

    unsigned pkE[4][2], pkO[4][2];
#pragma unroll
    for (int o = 0; o < 4; ++o) {
      pkE[o][0] = cvtpk(s2[cg][2 * o][0] * r, s2[cg][2 * o][1] * r);
      pkE[o][1] = cvtpk(s2[cg][2 * o][2] * r, s2[cg][2 * o][3] * r);
      pkO[o][0] = cvtpk(s2[cg][2 * o + 1][0] * r, s2[cg][2 * o + 1][1] * r);
      pkO[o][1] = cvtpk(s2[cg][2 * o + 1][2] * r, s2[cg][2 * o + 1][3] * r);
    }
    // round 1 (xor32): h0,h1 send pkO (keep pkE); h2,h3 send pkE (keep pkO)
    const bool lowHi = (hi < 2);
    unsigned keepR[4][2], gotR[4][2];
#pragma unroll
    for (int o = 0; o < 4; ++o)
#pragma unroll
      for (int e = 0; e < 2; ++e) {
        unsigned snd = lowHi ? pkO[o][e] : pkE[o][e];
        keepR[o][e] = lowHi ? pkE[o][e] : pkO[o][e];
        gotR[o][e] = __shfl_xor(snd, 32, 64);
      }
    // round 2 (xor16): h0,h3 send gotR ; h1,h2 send keepR
    const bool fwdGot = (hi == 0) || (hi == 3);
    unsigned recv2[4][2];
#pragma unroll
    for (int o = 0; o < 4; ++o)
#pragma unroll
      for (int e = 0; e < 2; ++e) {
        unsigned snd = fwdGot ? gotR[o][e] : keepR[o][e];
        recv2[o][e] = __shfl_xor(snd, 16, 64);
      }
    //   setA (lower class): h0 keepR, h1 recv2, h2 gotR, h3 recv2
    //   setB (upper class): h0 recv2, h1 gotR, h2 recv2, h3 keepR
#pragma unroll
    for (int o = 0; o < 4; ++o)
#pragma unroll
      for (int e = 0; e < 2; ++e) {
        setA[cg][o][e] = (hi & 1) ? recv2[o][e] : (hi == 0 ? keepR[o][e] : gotR[o][e]);
        setB[cg][o][e] = (hi & 1) ? (hi == 1 ? gotR[o][e] : keepR[o][e]) : recv2[o][e];
      }
  }

  // ---- PV: O[q][d] = P @ V  (A-frag from registers, B-frag from vt) ----
  f32x4 o2[2][4];
#pragma unroll
  for (int cg = 0; cg < 2; ++cg)
#pragma unroll
    for (int ni = 0; ni < 4; ++ni) o2[cg][ni] = f32x4{0.f, 0.f, 0.f, 0.f};
  __builtin_amdgcn_s_setprio(1);
#pragma unroll
  for (int ks = 0; ks < 4; ++ks) {
    const int cch = hi + ks * 4;
    bf16x8 pa[2];
#pragma unroll
    for (int cg = 0; cg < 2; ++cg) {
      u32x4 t;
      t[0] = setA[cg][ks][0]; t[1] = setA[cg][ks][1];
      t[2] = setB[cg][ks][0]; t[3] = setB[cg][ks][1];
      pa[cg] = __builtin_bit_cast(bf16x8, t);
    }
#pragma unroll
    for (int ni = 0; ni < 4; ++ni) {
      const int vr = ni * 16 + lo;
      const int cs = (cch & 8) | ((cch & 7) ^ (vr & 7));
      bf16x8 vf = *(const bf16x8*)&vt[vr * 128 + cs * 8];
      o2[0][ni] = __builtin_amdgcn_mfma_f32_16x16x32_bf16(pa[0], vf, o2[0][ni], 0, 0, 0);
      o2[1][ni] = __builtin_amdgcn_mfma_f32_16x16x32_bf16(pa[1], vf, o2[1][ni], 0, 0, 0);
    }
  }
  __builtin_amdgcn_s_setprio(0);

  // ---- store (P already normalized); ao stays [token][512] for gemm2 ----
#pragma unroll
  for (int cg = 0; cg < 2; ++cg)
#pragma unroll
    for (int j = 0; j < 4; ++j) {
      const int q = wid * 32 + cg * 16 + hi * 4 + j;
      const size_t obase = ((size_t)(b * 16384 + q * 128 + w)) * 512 + (size_t)n * 64;
#pragma unroll
      for (int ni = 0; ni < 4; ++ni)
        ao[obase + ni * 16 + lo] = f2b(o2[cg][ni][j]);
    }
}

// ---------------- launch ----------------
// ws: qkv panels [0,192MiB) | xb [192,224) | weights [224,~226)
// ao (bf16, 64 MB) lives IN d_out; gemm2 runs in-place (each block reads only its
// own 256 rows as bf16 before overwriting them as f32 -> race-free, deterministic).

extern "C" void kernel_launch(void* const* d_in, const int* in_sizes, int n_in,
                              void* d_out, int out_size, void* d_ws, size_t ws_size,
                              hipStream_t stream) {
  (void)in_sizes; (void)n_in; (void)out_size; (void)ws_size;
  const float* x  = (const float*)d_in[0];
  const float* Wq = (const float*)d_in[1];
  const float* bq = (const float*)d_in[2];
  const float* Wk = (const float*)d_in[3];
  const float* bk = (const float*)d_in[4];
  const float* Wv = (const float*)d_in[5];
  const float* bv = (const float*)d_in[6];
  const float* Wo = (const float*)d_in[7];
  const float* bo = (const float*)d_in[8];
  float* out = (float*)d_out;

  char* ws = (char*)d_ws;
  const size_t MiB = (size_t)1 << 20;
  u16* qkv   = (u16*)ws;
  u16* xb    = (u16*)(ws + 192 * MiB);
  u16* wqkvT = (u16*)(ws + 224 * MiB);
  u16* woT   = wqkvT + 1536 * 256;
  float* bqkv = (float*)(woT + 256 * 512);

  prep_x<<<2048, 256, 0, stream>>>(x, xb);
  prep_w<<<512, 256, 0, stream>>>(Wq, Wk, Wv, Wo, bq, bk, bv, wqkvT, woT, bqkv);

  gemm256<256, 2><<<1536, 1024, 0, stream>>>(xb, wqkvT, bqkv, qkv, 1536);
  attn_axial<<<4096, 256, 0, stream>>>(qkv, (u16*)out);
  gemm256<512, 0><<<256, 1024, 0, stream>>>((const u16*)out, woT, bo, out, 256);
}